// Round 7
// baseline (248.738 us; speedup 1.0000x reference)
//
#include <hip/hip_runtime.h>
#include <hip/hip_bf16.h>

#define NTOK 8192
#define DIM  512
#define HID  2048
#define NEXP 8
#define GFD  1024
#define NPAIR (NTOK*2)
#define EPSD 2.220446049250313e-16f

typedef __bf16 bf16;
typedef __bf16 bf16x4 __attribute__((ext_vector_type(4)));
typedef __bf16 bf16x8 __attribute__((ext_vector_type(8)));
typedef float  f32x4  __attribute__((ext_vector_type(4)));

// ---------------------------------------------------------------- conversions
__device__ __forceinline__ void cvt4(const float* __restrict__ src,
                                     bf16* __restrict__ dst, int i) {
    float4 v = ((const float4*)src)[i];
    bf16x4 o = { (bf16)v.x, (bf16)v.y, (bf16)v.z, (bf16)v.w };
    ((bf16x4*)dst)[i] = o;
}

__global__ __launch_bounds__(256) void convert_kernel(
    const float* __restrict__ x, const float* __restrict__ w1,
    const float* __restrict__ w2,
    bf16* __restrict__ xo, bf16* __restrict__ w1o, bf16* __restrict__ w2o)
{
    int tid = blockIdx.x * 256 + threadIdx.x;
    int stride = gridDim.x * 256;
    for (int i = tid; i < NTOK*DIM/4; i += stride)      cvt4(x,  xo,  i);
    for (int i = tid; i < NEXP*HID*DIM/4; i += stride)  cvt4(w1, w1o, i);
    for (int i = tid; i < NEXP*DIM*HID/4; i += stride)  cvt4(w2, w2o, i);
}

// ---------------------------------------------------------------- gating GEMM (f32, tiled)
__global__ __launch_bounds__(256) void gate_gemm_kernel(
    const float* __restrict__ gf, const float* __restrict__ wg,
    const float* __restrict__ wn, float* __restrict__ partial)
{
    const int bt = blockIdx.x;      // token tile 0..63
    const int bd = blockIdx.y;      // d chunk   0..7
    const int tid = threadIdx.x;

    __shared__ float sgf[128*129];
    __shared__ float sw[128][16];

    #pragma unroll
    for (int i = 0; i < 4; ++i) {
        int idx = i*256 + tid;              // 0..1023
        sw[idx>>3][idx&7]     = wg[bd*1024 + idx];
        sw[idx>>3][8+(idx&7)] = wn[bd*1024 + idx];
    }
    const float4* gf4 = (const float4*)gf;
    #pragma unroll
    for (int i = 0; i < 16; ++i) {
        int c = i*256 + tid;                // float4 chunk 0..4095
        int row = c >> 5, c4 = c & 31;
        float4 v = gf4[(size_t)(bt*128+row)*(GFD/4) + bd*32 + c4];
        float* dst = sgf + row*129 + c4*4;
        dst[0]=v.x; dst[1]=v.y; dst[2]=v.z; dst[3]=v.w;
    }
    __syncthreads();

    const int og = tid >> 6;
    const int lane = tid & 63;
    const int t0 = lane*2, t1 = t0+1;
    float a0=0,a1=0,a2=0,a3=0, b0=0,b1=0,b2=0,b3=0;
    #pragma unroll 4
    for (int dd = 0; dd < 128; ++dd) {
        float f0 = sgf[t0*129+dd];
        float f1 = sgf[t1*129+dd];
        float4 w = *(const float4*)&sw[dd][og*4];
        a0 += f0*w.x; a1 += f0*w.y; a2 += f0*w.z; a3 += f0*w.w;
        b0 += f1*w.x; b1 += f1*w.y; b2 += f1*w.z; b3 += f1*w.w;
    }
    size_t pbase = ((size_t)bd*NTOK + bt*128)*16 + og*4;
    *(float4*)&partial[pbase + (size_t)t0*16] = make_float4(a0,a1,a2,a3);
    *(float4*)&partial[pbase + (size_t)t1*16] = make_float4(b0,b1,b2,b3);
}

// ---------------------------------------------------------------- finalize
__global__ __launch_bounds__(256) void finalize_kernel(
    const float* __restrict__ partial, const float* __restrict__ noise,
    int* __restrict__ tok_e, float* __restrict__ tok_g, int* __restrict__ counts)
{
    __shared__ int hist[8];
    int tid = threadIdx.x;
    if (tid < 8) hist[tid] = 0;
    __syncthreads();
    int n = blockIdx.x*256 + tid;

    float lg[16];
    #pragma unroll
    for (int k = 0; k < 16; ++k) lg[k] = 0.f;
    #pragma unroll
    for (int j = 0; j < 8; ++j) {
        const float4* p = (const float4*)(partial + ((size_t)j*NTOK + n)*16);
        float4 q0 = p[0], q1 = p[1], q2 = p[2], q3 = p[3];
        lg[0]+=q0.x; lg[1]+=q0.y; lg[2]+=q0.z; lg[3]+=q0.w;
        lg[4]+=q1.x; lg[5]+=q1.y; lg[6]+=q1.z; lg[7]+=q1.w;
        lg[8]+=q2.x; lg[9]+=q2.y; lg[10]+=q2.z; lg[11]+=q2.w;
        lg[12]+=q3.x; lg[13]+=q3.y; lg[14]+=q3.z; lg[15]+=q3.w;
    }
    float v0=-1e30f, v1=-1e30f; int i0=0, i1=0;
    #pragma unroll
    for (int e = 0; e < 8; ++e) {
        float xn = lg[8+e];
        float sp = fmaxf(xn, 0.f) + log1pf(expf(-fabsf(xn)));   // exact softplus
        float l = lg[e] + noise[(size_t)n*NEXP+e] * (sp + 1e-2f);
        if (l > v0)      { v1=v0; i1=i0; v0=l; i0=e; }
        else if (l > v1) { v1=l; i1=e; }
    }
    float g1 = expf(v1 - v0);
    float s  = 1.0f + g1;
    tok_e[n] = i0 | (i1 << 8);
    tok_g[2*n]   = 1.0f / s;
    tok_g[2*n+1] = g1 / s;
    atomicAdd(&hist[i0], 1);
    atomicAdd(&hist[i1], 1);
    __syncthreads();
    if (tid < 8) atomicAdd(&counts[tid], hist[tid]);
}

__global__ void scan_kernel(const int* __restrict__ counts,
                            int* __restrict__ offsets, int* __restrict__ cursors)
{
    if (threadIdx.x == 0) {
        int s = 0;
        for (int e = 0; e < NEXP; ++e) { offsets[e] = s; cursors[e] = s; s += counts[e]; }
        offsets[NEXP] = s;
    }
}

// ---------------------------------------------------------------- dispatch (+ inverse map)
__global__ __launch_bounds__(256) void dispatch_kernel(
    const int* __restrict__ tok_e, const float* __restrict__ tok_g,
    int* __restrict__ cursors, int* __restrict__ pair_token, float* __restrict__ pair_gate,
    int* __restrict__ slot0, int* __restrict__ slot1)
{
    __shared__ int hist[8];
    __shared__ int base[8];
    int tid = threadIdx.x;
    if (tid < 8) hist[tid] = 0;
    __syncthreads();
    int n = blockIdx.x*256 + tid;
    int ee = tok_e[n];
    int e0 = ee & 255, e1 = (ee >> 8) & 255;
    atomicAdd(&hist[e0], 1);
    atomicAdd(&hist[e1], 1);
    __syncthreads();
    if (tid < 8) base[tid] = atomicAdd(&cursors[tid], hist[tid]);
    __syncthreads();
    int s0 = atomicAdd(&base[e0], 1);
    pair_token[s0] = n; pair_gate[s0] = tok_g[2*n];
    slot0[n] = s0;
    int s1 = atomicAdd(&base[e1], 1);
    pair_token[s1] = n; pair_gate[s1] = tok_g[2*n+1];
    slot1[n] = s1;
}

// ---------------------------------------------------------------- grouped GEMMs
#define GLL16(gsrc, ldst) \
    __builtin_amdgcn_global_load_lds( \
        (__attribute__((address_space(1))) void*)(gsrc), \
        (__attribute__((address_space(3))) void*)(ldst), 16, 0, 0)

// GEMM1: h[p, :] = gelu( x[token(p), :] @ fc1_w[e]^T )
// BM=256,BN=256,BK=64, 512 thr (8 waves 2Mx4N), dbuf 128 KB, nt-FASTEST grid
__global__ __launch_bounds__(512) void gemm1_kernel(
    const bf16* __restrict__ xb, const bf16* __restrict__ w1b,
    const float* __restrict__ fc1b,
    const int* __restrict__ pair_token, const int* __restrict__ offsets,
    bf16* __restrict__ hbuf)
{
    const int nt = blockIdx.x;            // 0..7  (HID/256)  FASTEST: A-sharers co-dispatch
    const int mt = blockIdx.y;            // 0..31
    const int e  = blockIdx.z;            // 0..7
    const int seg0 = offsets[e], seg1 = offsets[e+1];
    const int cnt = seg1 - seg0;
    const int mbase = mt * 256;
    if (mbase >= cnt) return;

    __shared__ bf16 ldsA[2][256*64];      // 32 KB each
    __shared__ bf16 ldsB[2][256*64];      // 32 KB each

    const int tid = threadIdx.x;
    const int wid = tid >> 6;
    const int lane = tid & 63;
    const int wr = wid >> 2, wc = wid & 3;   // 2M x 4N waves, wave tile 128x64

    const bf16* srcA[4];
    const bf16* srcB[4];
    #pragma unroll
    for (int i = 0; i < 4; ++i) {
        int c = i*512 + tid;              // 16B-chunk id 0..2047
        int r = c >> 3, c16 = c & 7;
        int sw = (c16 ^ (r & 7)) * 8;     // pre-swizzled source (T2)
        int p = seg0 + mbase + r;
        if (p > seg1 - 1) p = seg1 - 1;
        srcA[i] = xb + (size_t)pair_token[p] * DIM + sw;
        srcB[i] = w1b + ((size_t)e*HID + nt*256 + r) * DIM + sw;
    }

    f32x4 acc[8][4] = {};

#define STAGE1(buf, kk) do { \
    _Pragma("unroll") \
    for (int i = 0; i < 4; ++i) { \
        GLL16(srcA[i] + (kk), (char*)ldsA[buf] + i*8192 + tid*16); \
        GLL16(srcB[i] + (kk), (char*)ldsB[buf] + i*8192 + tid*16); \
    } } while (0)

    STAGE1(0, 0);
    __syncthreads();

    const int NT1 = DIM/64;               // 8
    for (int t = 0; t < NT1; ++t) {
        const int cur = t & 1;
        if (t + 1 < NT1) STAGE1(1-cur, (t+1)*64);
        #pragma unroll
        for (int ks = 0; ks < 2; ++ks) {
            bf16x8 bv[4];
            #pragma unroll
            for (int n = 0; n < 4; ++n) {
                int row = wc*64 + n*16 + (lane & 15);
                int sw = (ks*4 + (lane >> 4)) ^ (row & 7);
                bv[n] = *(const bf16x8*)(ldsB[cur] + row*64 + sw*8);
            }
            __builtin_amdgcn_s_setprio(1);
            #pragma unroll
            for (int m = 0; m < 8; ++m) {
                int row = wr*128 + m*16 + (lane & 15);
                int sw = (ks*4 + (lane >> 4)) ^ (row & 7);
                bf16x8 av = *(const bf16x8*)(ldsA[cur] + row*64 + sw*8);
                #pragma unroll
                for (int n = 0; n < 4; ++n)
                    acc[m][n] = __builtin_amdgcn_mfma_f32_16x16x32_bf16(
                        av, bv[n], acc[m][n], 0, 0, 0);
            }
            __builtin_amdgcn_s_setprio(0);
        }
        if (t + 1 < NT1) __syncthreads();
    }

    #pragma unroll
    for (int m = 0; m < 8; ++m) {
        #pragma unroll
        for (int jj = 0; jj < 4; ++jj) {
            int rt = wr*128 + m*16 + (lane >> 4)*4 + jj;
            int row = mbase + rt;
            if (row < cnt) {
                size_t hrow = (size_t)(seg0 + row) * HID;
                #pragma unroll
                for (int n = 0; n < 4; ++n) {
                    int col = nt*256 + wc*64 + n*16 + (lane & 15);
                    float v = acc[m][n][jj] + fc1b[e*HID + col];
                    float g = 0.5f * v * (1.0f + erff(v * 0.70710678118654752f));
                    hbuf[hrow + col] = (bf16)g;
                }
            }
        }
    }
}

// GEMM2: pout[p, :] = gate * exp( h[p, :] @ fc2_w[e]^T + b )
// BM=256,BN=128,BK=64, 512 thr (8 waves 4Mx2N), dbuf 96 KB, nt-FASTEST grid
__global__ __launch_bounds__(512) void gemm2_kernel(
    const bf16* __restrict__ hbuf, const bf16* __restrict__ w2b,
    const float* __restrict__ fc2b,
    const float* __restrict__ pair_gate,
    const int* __restrict__ offsets, bf16* __restrict__ pout)
{
    const int nt = blockIdx.x;            // 0..3  (DIM/128)  FASTEST
    const int mt = blockIdx.y;            // 0..31
    const int e  = blockIdx.z;
    const int seg0 = offsets[e], seg1 = offsets[e+1];
    const int cnt = seg1 - seg0;
    const int mbase = mt * 256;
    if (mbase >= cnt) return;

    __shared__ bf16 ldsA[2][256*64];      // 32 KB each
    __shared__ bf16 ldsB[2][128*64];      // 16 KB each

    const int tid = threadIdx.x;
    const int wid = tid >> 6;
    const int lane = tid & 63;
    const int wr = wid >> 1, wc = wid & 1;   // 4M x 2N waves, wave tile 64x64

    const bf16* srcA[4];
    const bf16* srcB[2];
    #pragma unroll
    for (int i = 0; i < 4; ++i) {
        int c = i*512 + tid;              // 0..2047
        int r = c >> 3, c16 = c & 7;
        int sw = (c16 ^ (r & 7)) * 8;
        int p = seg0 + mbase + r;
        if (p > seg1 - 1) p = seg1 - 1;
        srcA[i] = hbuf + (size_t)p * HID + sw;
    }
    #pragma unroll
    for (int i = 0; i < 2; ++i) {
        int c = i*512 + tid;              // 0..1023
        int r = c >> 3, c16 = c & 7;
        int sw = (c16 ^ (r & 7)) * 8;
        srcB[i] = w2b + ((size_t)e*DIM + nt*128 + r) * HID + sw;
    }

    f32x4 acc[4][4] = {};

#define STAGE2(buf, kk) do { \
    _Pragma("unroll") \
    for (int i = 0; i < 4; ++i) \
        GLL16(srcA[i] + (kk), (char*)ldsA[buf] + i*8192 + tid*16); \
    _Pragma("unroll") \
    for (int i = 0; i < 2; ++i) \
        GLL16(srcB[i] + (kk), (char*)ldsB[buf] + i*8192 + tid*16); \
    } while (0)

    STAGE2(0, 0);
    __syncthreads();

    const int NT2 = HID/64;               // 32
    for (int t = 0; t < NT2; ++t) {
        const int cur = t & 1;
        if (t + 1 < NT2) STAGE2(1-cur, (t+1)*64);
        #pragma unroll
        for (int ks = 0; ks < 2; ++ks) {
            bf16x8 bv[4];
            #pragma unroll
            for (int n = 0; n < 4; ++n) {
                int row = wc*64 + n*16 + (lane & 15);
                int sw = (ks*4 + (lane >> 4)) ^ (row & 7);
                bv[n] = *(const bf16x8*)(ldsB[cur] + row*64 + sw*8);
            }
            __builtin_amdgcn_s_setprio(1);
            #pragma unroll
            for (int m = 0; m < 4; ++m) {
                int row = wr*64 + m*16 + (lane & 15);
                int sw = (ks*4 + (lane >> 4)) ^ (row & 7);
                bf16x8 av = *(const bf16x8*)(ldsA[cur] + row*64 + sw*8);
                #pragma unroll
                for (int n = 0; n < 4; ++n)
                    acc[m][n] = __builtin_amdgcn_mfma_f32_16x16x32_bf16(
                        av, bv[n], acc[m][n], 0, 0, 0);
            }
            __builtin_amdgcn_s_setprio(0);
        }
        if (t + 1 < NT2) __syncthreads();
    }

    #pragma unroll
    for (int m = 0; m < 4; ++m) {
        #pragma unroll
        for (int jj = 0; jj < 4; ++jj) {
            int rt = wr*64 + m*16 + (lane >> 4)*4 + jj;
            int row = mbase + rt;
            if (row < cnt) {
                int p = seg0 + row;
                float gate = pair_gate[p];
                bf16* prow = pout + (size_t)p * DIM;
                #pragma unroll
                for (int n = 0; n < 4; ++n) {
                    int col = nt*128 + wc*64 + n*16 + (lane & 15);
                    float v = acc[m][n][jj] + fc2b[e*DIM + col];
                    prow[col] = (bf16)(gate * expf(v));
                }
            }
        }
    }
}

// ---------------------------------------------------------------- combine: log(p0+p1), eps-guard
__global__ __launch_bounds__(256) void combine_kernel(
    const bf16* __restrict__ pout, const int* __restrict__ slot0,
    const int* __restrict__ slot1, float* __restrict__ out)
{
    const int wid = threadIdx.x >> 6;
    const int lane = threadIdx.x & 63;
    const int n = blockIdx.x*4 + wid;           // one wave per token
    const int s0 = slot0[n], s1 = slot1[n];
    bf16x8 a = ((const bf16x8*)(pout + (size_t)s0 * DIM))[lane];
    bf16x8 b = ((const bf16x8*)(pout + (size_t)s1 * DIM))[lane];
    float4 r0, r1;
    float* orow = out + (size_t)n * DIM + lane*8;
    float c;
    c = (float)a[0] + (float)b[0]; r0.x = logf(c == 0.f ? EPSD : c);
    c = (float)a[1] + (float)b[1]; r0.y = logf(c == 0.f ? EPSD : c);
    c = (float)a[2] + (float)b[2]; r0.z = logf(c == 0.f ? EPSD : c);
    c = (float)a[3] + (float)b[3]; r0.w = logf(c == 0.f ? EPSD : c);
    c = (float)a[4] + (float)b[4]; r1.x = logf(c == 0.f ? EPSD : c);
    c = (float)a[5] + (float)b[5]; r1.y = logf(c == 0.f ? EPSD : c);
    c = (float)a[6] + (float)b[6]; r1.z = logf(c == 0.f ? EPSD : c);
    c = (float)a[7] + (float)b[7]; r1.w = logf(c == 0.f ? EPSD : c);
    ((float4*)orow)[0] = r0;
    ((float4*)orow)[1] = r1;
}

// ---------------------------------------------------------------- launch
extern "C" void kernel_launch(void* const* d_in, const int* in_sizes, int n_in,
                              void* d_out, int out_size, void* d_ws, size_t ws_size,
                              hipStream_t stream)
{
    const float* x     = (const float*)d_in[0];
    const float* gf    = (const float*)d_in[1];
    const float* noise = (const float*)d_in[2];
    const float* wg    = (const float*)d_in[3];
    const float* wn    = (const float*)d_in[4];
    const float* fc1w  = (const float*)d_in[5];
    const float* fc1b  = (const float*)d_in[6];
    const float* fc2w  = (const float*)d_in[7];
    const float* fc2b  = (const float*)d_in[8];
    float* out = (float*)d_out;

    char* ws = (char*)d_ws;
    size_t off = 0;
    bf16* xb  = (bf16*)(ws + off); off += (size_t)NTOK*DIM*2;        // 8 MB
    bf16* w1b = (bf16*)(ws + off); off += (size_t)NEXP*HID*DIM*2;    // 16 MB
    bf16* w2b = (bf16*)(ws + off); off += (size_t)NEXP*DIM*HID*2;    // 16 MB
    bf16* hb  = (bf16*)(ws + off); off += (size_t)NPAIR*HID*2;       // 64 MB
    int*   pair_token = (int*)  (ws + off); off += (size_t)NPAIR*4;
    float* pair_gate  = (float*)(ws + off); off += (size_t)NPAIR*4;
    int*   tok_e      = (int*)  (ws + off); off += (size_t)NTOK*4;
    float* tok_g      = (float*)(ws + off); off += (size_t)NTOK*2*4;
    int*   slot0      = (int*)  (ws + off); off += (size_t)NTOK*4;
    int*   slot1      = (int*)  (ws + off); off += (size_t)NTOK*4;
    int*   counts     = (int*)  (ws + off); off += 64;
    int*   offsets    = (int*)  (ws + off); off += 64;
    int*   cursors    = (int*)  (ws + off); off += 64;
    if (ws_size < off) return;   // workspace too small — visible as absmax fail

    // gating partials alias hb (finalize reads them before gemm1 writes hb)
    float* partial = (float*)hb;       // 4 MB << 64 MB
    // per-pair outputs alias xb/w1b (dead after gemm1; gemm2 runs strictly after)
    bf16* pout = (bf16*)ws;            // 16384*512*2 = 16 MB < 24 MB (xb+w1b)

    hipMemsetAsync(counts, 0, 32, stream);
    convert_kernel<<<2048, 256, 0, stream>>>(x, fc1w, fc2w, xb, w1b, w2b);
    gate_gemm_kernel<<<dim3(64, 8), 256, 0, stream>>>(gf, wg, wn, partial);
    finalize_kernel<<<NTOK/256, 256, 0, stream>>>(partial, noise, tok_e, tok_g, counts);
    scan_kernel<<<1, 64, 0, stream>>>(counts, offsets, cursors);
    dispatch_kernel<<<NTOK/256, 256, 0, stream>>>(tok_e, tok_g, cursors,
                                                  pair_token, pair_gate, slot0, slot1);
    gemm1_kernel<<<dim3(8, 32, 8), 512, 0, stream>>>(xb, w1b, fc1b, pair_token, offsets, hb);
    gemm2_kernel<<<dim3(4, 32, 8), 512, 0, stream>>>(hb, w2b, fc2b, pair_gate, offsets, pout);
    combine_kernel<<<NTOK/4, 256, 0, stream>>>(pout, slot0, slot1, out);
}

// Round 8
// 197.228 us; speedup vs baseline: 1.2612x; 1.2612x over previous
//
#include <hip/hip_runtime.h>
#include <hip/hip_bf16.h>

#define NTOK 8192
#define DIM  512
#define HID  2048
#define NEXP 8
#define GFD  1024
#define NPAIR (NTOK*2)
#define EPSD 2.220446049250313e-16f
#define MAXTILES 136

typedef __bf16 bf16;
typedef __bf16 bf16x4 __attribute__((ext_vector_type(4)));
typedef __bf16 bf16x8 __attribute__((ext_vector_type(8)));
typedef float  f32x4  __attribute__((ext_vector_type(4)));

// ---------------------------------------------------------------- conversions
__device__ __forceinline__ void cvt4(const float* __restrict__ src,
                                     bf16* __restrict__ dst, int i) {
    float4 v = ((const float4*)src)[i];
    bf16x4 o = { (bf16)v.x, (bf16)v.y, (bf16)v.z, (bf16)v.w };
    ((bf16x4*)dst)[i] = o;
}

__global__ __launch_bounds__(256) void convert_kernel(
    const float* __restrict__ x, const float* __restrict__ w1,
    const float* __restrict__ w2,
    bf16* __restrict__ xo, bf16* __restrict__ w1o, bf16* __restrict__ w2o)
{
    int tid = blockIdx.x * 256 + threadIdx.x;
    int stride = gridDim.x * 256;
    for (int i = tid; i < NTOK*DIM/4; i += stride)      cvt4(x,  xo,  i);
    for (int i = tid; i < NEXP*HID*DIM/4; i += stride)  cvt4(w1, w1o, i);
    for (int i = tid; i < NEXP*DIM*HID/4; i += stride)  cvt4(w2, w2o, i);
}

// ---------------------------------------------------------------- gating GEMM (f32, tiled)
__global__ __launch_bounds__(256) void gate_gemm_kernel(
    const float* __restrict__ gf, const float* __restrict__ wg,
    const float* __restrict__ wn, float* __restrict__ partial)
{
    const int bt = blockIdx.x;      // token tile 0..63
    const int bd = blockIdx.y;      // d chunk   0..7
    const int tid = threadIdx.x;

    __shared__ float sgf[128*129];
    __shared__ float sw[128][16];

    #pragma unroll
    for (int i = 0; i < 4; ++i) {
        int idx = i*256 + tid;              // 0..1023
        sw[idx>>3][idx&7]     = wg[bd*1024 + idx];
        sw[idx>>3][8+(idx&7)] = wn[bd*1024 + idx];
    }
    const float4* gf4 = (const float4*)gf;
    #pragma unroll
    for (int i = 0; i < 16; ++i) {
        int c = i*256 + tid;                // float4 chunk 0..4095
        int row = c >> 5, c4 = c & 31;
        float4 v = gf4[(size_t)(bt*128+row)*(GFD/4) + bd*32 + c4];
        float* dst = sgf + row*129 + c4*4;
        dst[0]=v.x; dst[1]=v.y; dst[2]=v.z; dst[3]=v.w;
    }
    __syncthreads();

    const int og = tid >> 6;
    const int lane = tid & 63;
    const int t0 = lane*2, t1 = t0+1;
    float a0=0,a1=0,a2=0,a3=0, b0=0,b1=0,b2=0,b3=0;
    #pragma unroll 4
    for (int dd = 0; dd < 128; ++dd) {
        float f0 = sgf[t0*129+dd];
        float f1 = sgf[t1*129+dd];
        float4 w = *(const float4*)&sw[dd][og*4];
        a0 += f0*w.x; a1 += f0*w.y; a2 += f0*w.z; a3 += f0*w.w;
        b0 += f1*w.x; b1 += f1*w.y; b2 += f1*w.z; b3 += f1*w.w;
    }
    size_t pbase = ((size_t)bd*NTOK + bt*128)*16 + og*4;
    *(float4*)&partial[pbase + (size_t)t0*16] = make_float4(a0,a1,a2,a3);
    *(float4*)&partial[pbase + (size_t)t1*16] = make_float4(b0,b1,b2,b3);
}

// ---------------------------------------------------------------- finalize
__global__ __launch_bounds__(256) void finalize_kernel(
    const float* __restrict__ partial, const float* __restrict__ noise,
    int* __restrict__ tok_e, float* __restrict__ tok_g, int* __restrict__ counts)
{
    __shared__ int hist[8];
    int tid = threadIdx.x;
    if (tid < 8) hist[tid] = 0;
    __syncthreads();
    int n = blockIdx.x*256 + tid;

    float lg[16];
    #pragma unroll
    for (int k = 0; k < 16; ++k) lg[k] = 0.f;
    #pragma unroll
    for (int j = 0; j < 8; ++j) {
        const float4* p = (const float4*)(partial + ((size_t)j*NTOK + n)*16);
        float4 q0 = p[0], q1 = p[1], q2 = p[2], q3 = p[3];
        lg[0]+=q0.x; lg[1]+=q0.y; lg[2]+=q0.z; lg[3]+=q0.w;
        lg[4]+=q1.x; lg[5]+=q1.y; lg[6]+=q1.z; lg[7]+=q1.w;
        lg[8]+=q2.x; lg[9]+=q2.y; lg[10]+=q2.z; lg[11]+=q2.w;
        lg[12]+=q3.x; lg[13]+=q3.y; lg[14]+=q3.z; lg[15]+=q3.w;
    }
    float v0=-1e30f, v1=-1e30f; int i0=0, i1=0;
    #pragma unroll
    for (int e = 0; e < 8; ++e) {
        float xn = lg[8+e];
        float sp = fmaxf(xn, 0.f) + log1pf(expf(-fabsf(xn)));   // exact softplus
        float l = lg[e] + noise[(size_t)n*NEXP+e] * (sp + 1e-2f);
        if (l > v0)      { v1=v0; i1=i0; v0=l; i0=e; }
        else if (l > v1) { v1=l; i1=e; }
    }
    float g1 = expf(v1 - v0);
    float s  = 1.0f + g1;
    tok_e[n] = i0 | (i1 << 8);
    tok_g[2*n]   = 1.0f / s;
    tok_g[2*n+1] = g1 / s;
    atomicAdd(&hist[i0], 1);
    atomicAdd(&hist[i1], 1);
    __syncthreads();
    if (tid < 8) atomicAdd(&counts[tid], hist[tid]);
}

// ---------------------------------------------------------------- scan + tile list
__global__ void scan_kernel(const int* __restrict__ counts,
                            int* __restrict__ offsets, int* __restrict__ cursors,
                            int* __restrict__ tlist, int* __restrict__ ntiles)
{
    if (threadIdx.x == 0) {
        int s = 0, nt = 0;
        for (int e = 0; e < NEXP; ++e) {
            offsets[e] = s; cursors[e] = s;
            int c = counts[e];
            for (int mt = 0; mt*128 < c; ++mt) tlist[nt++] = e | (mt << 8);
            s += c;
        }
        offsets[NEXP] = s;
        ntiles[0] = nt;
    }
}

// ---------------------------------------------------------------- dispatch (+ inverse map)
__global__ __launch_bounds__(256) void dispatch_kernel(
    const int* __restrict__ tok_e, const float* __restrict__ tok_g,
    int* __restrict__ cursors, int* __restrict__ pair_token, float* __restrict__ pair_gate,
    int* __restrict__ slot0, int* __restrict__ slot1)
{
    __shared__ int hist[8];
    __shared__ int base[8];
    int tid = threadIdx.x;
    if (tid < 8) hist[tid] = 0;
    __syncthreads();
    int n = blockIdx.x*256 + tid;
    int ee = tok_e[n];
    int e0 = ee & 255, e1 = (ee >> 8) & 255;
    atomicAdd(&hist[e0], 1);
    atomicAdd(&hist[e1], 1);
    __syncthreads();
    if (tid < 8) base[tid] = atomicAdd(&cursors[tid], hist[tid]);
    __syncthreads();
    int s0 = atomicAdd(&base[e0], 1);
    pair_token[s0] = n; pair_gate[s0] = tok_g[2*n];
    slot0[n] = s0;
    int s1 = atomicAdd(&base[e1], 1);
    pair_token[s1] = n; pair_gate[s1] = tok_g[2*n+1];
    slot1[n] = s1;
}

// ---------------------------------------------------------------- grouped GEMMs
#define GLL16(gsrc, ldst) \
    __builtin_amdgcn_global_load_lds( \
        (__attribute__((address_space(1))) void*)(gsrc), \
        (__attribute__((address_space(3))) void*)(ldst), 16, 0, 0)

// GEMM1: h[p, :] = gelu( x[token(p), :] @ fc1_w[e]^T )
// BM=128, BN=256 (nt-paired), BK=64, 512 thr (8 waves 2Mx4N), single-buffer 48 KB LDS,
// compact tile grid, nt-fastest.
__global__ __launch_bounds__(512) void gemm1_kernel(
    const bf16* __restrict__ xb, const bf16* __restrict__ w1b,
    const float* __restrict__ fc1b,
    const int* __restrict__ pair_token, const int* __restrict__ offsets,
    const int* __restrict__ tlist, const int* __restrict__ ntiles,
    bf16* __restrict__ hbuf)
{
    const int ntp = blockIdx.x;           // 0..7  (HID/256)  FASTEST: A-sharers co-dispatch
    const int tix = blockIdx.y;
    if (tix >= ntiles[0]) return;
    const int code = tlist[tix];
    const int e  = code & 255;
    const int mt = code >> 8;
    const int seg0 = offsets[e], seg1 = offsets[e+1];
    const int cnt = seg1 - seg0;
    const int mbase = mt * 128;

    __shared__ bf16 ldsA[128*64];         // 16 KB
    __shared__ bf16 ldsB[256*64];         // 32 KB (two 128-col halves)

    const int tid = threadIdx.x;
    const int wid = tid >> 6;
    const int lane = tid & 63;
    const int wr = wid >> 2, wc = wid & 3;   // 2M x 4N waves, wave tile 64x64

    const bf16* srcA[2];
    const bf16* srcB[4];
    #pragma unroll
    for (int i = 0; i < 2; ++i) {
        int c = i*512 + tid;              // 16B-chunk id 0..1023
        int r = c >> 3, c16 = c & 7;
        int sw = (c16 ^ (r & 7)) * 8;     // pre-swizzled source (T2)
        int p = seg0 + mbase + r;
        if (p > seg1 - 1) p = seg1 - 1;
        srcA[i] = xb + (size_t)pair_token[p] * DIM + sw;
    }
    #pragma unroll
    for (int i = 0; i < 4; ++i) {
        int c = i*512 + tid;              // 0..2047
        int r = c >> 3, c16 = c & 7;      // r = B row = output col 0..255
        int sw = (c16 ^ (r & 7)) * 8;
        srcB[i] = w1b + ((size_t)e*HID + ntp*256 + r) * DIM + sw;
    }

    f32x4 acc[4][4] = {};

    for (int kk = 0; kk < DIM; kk += 64) {
        #pragma unroll
        for (int i = 0; i < 2; ++i)
            GLL16(srcA[i] + kk, (char*)ldsA + i*8192 + tid*16);
        #pragma unroll
        for (int i = 0; i < 4; ++i)
            GLL16(srcB[i] + kk, (char*)ldsB + i*8192 + tid*16);
        __syncthreads();
        #pragma unroll
        for (int ks = 0; ks < 2; ++ks) {
            bf16x8 av[4], bv[4];
            #pragma unroll
            for (int m = 0; m < 4; ++m) {
                int row = wr*64 + m*16 + (lane & 15);
                int sw = (ks*4 + (lane >> 4)) ^ (row & 7);
                av[m] = *(const bf16x8*)(ldsA + row*64 + sw*8);
            }
            #pragma unroll
            for (int n = 0; n < 4; ++n) {
                int row = wc*64 + n*16 + (lane & 15);      // 0..255
                int sw = (ks*4 + (lane >> 4)) ^ (row & 7);
                bv[n] = *(const bf16x8*)(ldsB + row*64 + sw*8);
            }
            __builtin_amdgcn_s_setprio(1);
            #pragma unroll
            for (int m = 0; m < 4; ++m)
                #pragma unroll
                for (int n = 0; n < 4; ++n)
                    acc[m][n] = __builtin_amdgcn_mfma_f32_16x16x32_bf16(
                        av[m], bv[n], acc[m][n], 0, 0, 0);
            __builtin_amdgcn_s_setprio(0);
        }
        __syncthreads();
    }

    #pragma unroll
    for (int m = 0; m < 4; ++m) {
        #pragma unroll
        for (int jj = 0; jj < 4; ++jj) {
            int rt = wr*64 + m*16 + (lane >> 4)*4 + jj;
            int row = mbase + rt;
            if (row < cnt) {
                size_t hrow = (size_t)(seg0 + row) * HID;
                #pragma unroll
                for (int n = 0; n < 4; ++n) {
                    int col = ntp*256 + wc*64 + n*16 + (lane & 15);
                    float v = acc[m][n][jj] + fc1b[e*HID + col];
                    float g = 0.5f * v * (1.0f + erff(v * 0.70710678118654752f));
                    hbuf[hrow + col] = (bf16)g;
                }
            }
        }
    }
}

// GEMM2: pout[p, :] = gate * exp( h[p, :] @ fc2_w[e]^T + b )
// r6-proven body: BM=128, BN=128, BK=64, 256 thr, single-buffer, compact tile grid.
__global__ __launch_bounds__(256) void gemm2_kernel(
    const bf16* __restrict__ hbuf, const bf16* __restrict__ w2b,
    const float* __restrict__ fc2b,
    const float* __restrict__ pair_gate,
    const int* __restrict__ offsets,
    const int* __restrict__ tlist, const int* __restrict__ ntiles,
    bf16* __restrict__ pout)
{
    const int nt = blockIdx.x;            // 0..3   (DIM/128)  FASTEST
    const int tix = blockIdx.y;
    if (tix >= ntiles[0]) return;
    const int code = tlist[tix];
    const int e  = code & 255;
    const int mt = code >> 8;
    const int seg0 = offsets[e], seg1 = offsets[e+1];
    const int cnt = seg1 - seg0;
    const int mbase = mt * 128;

    __shared__ bf16 ldsA[128*64];
    __shared__ bf16 ldsB[128*64];

    const int tid = threadIdx.x;
    const int wid = tid >> 6;
    const int lane = tid & 63;
    const int wr = wid >> 1, wc = wid & 1;

    const bf16* srcA[4];
    const bf16* srcB[4];
    #pragma unroll
    for (int i = 0; i < 4; ++i) {
        int c = wid*256 + i*64 + lane;
        int r = c >> 3, c16 = c & 7;
        int sw = (c16 ^ (r & 7)) * 8;
        int p = seg0 + mbase + r;
        if (p > seg1 - 1) p = seg1 - 1;
        srcA[i] = hbuf + (size_t)p * HID + sw;
        srcB[i] = w2b + ((size_t)e*DIM + nt*128 + r) * HID + sw;
    }

    f32x4 acc[4][4] = {};

    for (int kk = 0; kk < HID; kk += 64) {
        #pragma unroll
        for (int i = 0; i < 4; ++i) {
            GLL16(srcA[i] + kk, (char*)ldsA + wid*4096 + i*1024);
            GLL16(srcB[i] + kk, (char*)ldsB + wid*4096 + i*1024);
        }
        __syncthreads();
        #pragma unroll
        for (int ks = 0; ks < 2; ++ks) {
            bf16x8 av[4], bv[4];
            #pragma unroll
            for (int m = 0; m < 4; ++m) {
                int row = wr*64 + m*16 + (lane & 15);
                int sw = (ks*4 + (lane >> 4)) ^ (row & 7);
                av[m] = *(const bf16x8*)(ldsA + row*64 + sw*8);
            }
            #pragma unroll
            for (int n = 0; n < 4; ++n) {
                int row = wc*64 + n*16 + (lane & 15);
                int sw = (ks*4 + (lane >> 4)) ^ (row & 7);
                bv[n] = *(const bf16x8*)(ldsB + row*64 + sw*8);
            }
            __builtin_amdgcn_s_setprio(1);
            #pragma unroll
            for (int m = 0; m < 4; ++m)
                #pragma unroll
                for (int n = 0; n < 4; ++n)
                    acc[m][n] = __builtin_amdgcn_mfma_f32_16x16x32_bf16(
                        av[m], bv[n], acc[m][n], 0, 0, 0);
            __builtin_amdgcn_s_setprio(0);
        }
        __syncthreads();
    }

    #pragma unroll
    for (int m = 0; m < 4; ++m) {
        #pragma unroll
        for (int jj = 0; jj < 4; ++jj) {
            int rt = wr*64 + m*16 + (lane >> 4)*4 + jj;
            int row = mbase + rt;
            if (row < cnt) {
                int p = seg0 + row;
                float gate = pair_gate[p];
                bf16* prow = pout + (size_t)p * DIM;
                #pragma unroll
                for (int n = 0; n < 4; ++n) {
                    int col = nt*128 + wc*64 + n*16 + (lane & 15);
                    float v = acc[m][n][jj] + fc2b[e*DIM + col];
                    prow[col] = (bf16)(gate * expf(v));
                }
            }
        }
    }
}

// ---------------------------------------------------------------- combine: log(p0+p1), eps-guard
__global__ __launch_bounds__(256) void combine_kernel(
    const bf16* __restrict__ pout, const int* __restrict__ slot0,
    const int* __restrict__ slot1, float* __restrict__ out)
{
    const int wid = threadIdx.x >> 6;
    const int lane = threadIdx.x & 63;
    const int n = blockIdx.x*4 + wid;           // one wave per token
    const int s0 = slot0[n], s1 = slot1[n];
    bf16x8 a = ((const bf16x8*)(pout + (size_t)s0 * DIM))[lane];
    bf16x8 b = ((const bf16x8*)(pout + (size_t)s1 * DIM))[lane];
    float4 r0, r1;
    float* orow = out + (size_t)n * DIM + lane*8;
    float c;
    c = (float)a[0] + (float)b[0]; r0.x = logf(c == 0.f ? EPSD : c);
    c = (float)a[1] + (float)b[1]; r0.y = logf(c == 0.f ? EPSD : c);
    c = (float)a[2] + (float)b[2]; r0.z = logf(c == 0.f ? EPSD : c);
    c = (float)a[3] + (float)b[3]; r0.w = logf(c == 0.f ? EPSD : c);
    c = (float)a[4] + (float)b[4]; r1.x = logf(c == 0.f ? EPSD : c);
    c = (float)a[5] + (float)b[5]; r1.y = logf(c == 0.f ? EPSD : c);
    c = (float)a[6] + (float)b[6]; r1.z = logf(c == 0.f ? EPSD : c);
    c = (float)a[7] + (float)b[7]; r1.w = logf(c == 0.f ? EPSD : c);
    ((float4*)orow)[0] = r0;
    ((float4*)orow)[1] = r1;
}

// ---------------------------------------------------------------- launch
extern "C" void kernel_launch(void* const* d_in, const int* in_sizes, int n_in,
                              void* d_out, int out_size, void* d_ws, size_t ws_size,
                              hipStream_t stream)
{
    const float* x     = (const float*)d_in[0];
    const float* gf    = (const float*)d_in[1];
    const float* noise = (const float*)d_in[2];
    const float* wg    = (const float*)d_in[3];
    const float* wn    = (const float*)d_in[4];
    const float* fc1w  = (const float*)d_in[5];
    const float* fc1b  = (const float*)d_in[6];
    const float* fc2w  = (const float*)d_in[7];
    const float* fc2b  = (const float*)d_in[8];
    float* out = (float*)d_out;

    char* ws = (char*)d_ws;
    size_t off = 0;
    bf16* xb  = (bf16*)(ws + off); off += (size_t)NTOK*DIM*2;        // 8 MB
    bf16* w1b = (bf16*)(ws + off); off += (size_t)NEXP*HID*DIM*2;    // 16 MB
    bf16* w2b = (bf16*)(ws + off); off += (size_t)NEXP*DIM*HID*2;    // 16 MB
    bf16* hb  = (bf16*)(ws + off); off += (size_t)NPAIR*HID*2;       // 64 MB
    int*   pair_token = (int*)  (ws + off); off += (size_t)NPAIR*4;
    float* pair_gate  = (float*)(ws + off); off += (size_t)NPAIR*4;
    int*   tok_e      = (int*)  (ws + off); off += (size_t)NTOK*4;
    float* tok_g      = (float*)(ws + off); off += (size_t)NTOK*2*4;
    int*   slot0      = (int*)  (ws + off); off += (size_t)NTOK*4;
    int*   slot1      = (int*)  (ws + off); off += (size_t)NTOK*4;
    int*   counts     = (int*)  (ws + off); off += 64;
    int*   offsets    = (int*)  (ws + off); off += 64;
    int*   cursors    = (int*)  (ws + off); off += 64;
    int*   tlist      = (int*)  (ws + off); off += MAXTILES*4;
    int*   ntiles     = (int*)  (ws + off); off += 64;
    if (ws_size < off) return;   // workspace too small — visible as absmax fail

    // gating partials alias hb (finalize reads them before gemm1 writes hb)
    float* partial = (float*)hb;       // 4 MB << 64 MB
    // per-pair outputs alias xb/w1b (dead after gemm1; gemm2 runs strictly after)
    bf16* pout = (bf16*)ws;            // 16384*512*2 = 16 MB < 24 MB (xb+w1b)

    hipMemsetAsync(counts, 0, 32, stream);
    convert_kernel<<<2048, 256, 0, stream>>>(x, fc1w, fc2w, xb, w1b, w2b);
    gate_gemm_kernel<<<dim3(64, 8), 256, 0, stream>>>(gf, wg, wn, partial);
    finalize_kernel<<<NTOK/256, 256, 0, stream>>>(partial, noise, tok_e, tok_g, counts);
    scan_kernel<<<1, 64, 0, stream>>>(counts, offsets, cursors, tlist, ntiles);
    dispatch_kernel<<<NTOK/256, 256, 0, stream>>>(tok_e, tok_g, cursors,
                                                  pair_token, pair_gate, slot0, slot1);
    gemm1_kernel<<<dim3(8, MAXTILES), 512, 0, stream>>>(xb, w1b, fc1b, pair_token, offsets,
                                                        tlist, ntiles, hb);
    gemm2_kernel<<<dim3(4, MAXTILES), 256, 0, stream>>>(hb, w2b, fc2b, pair_gate, offsets,
                                                        tlist, ntiles, pout);
    combine_kernel<<<NTOK/4, 256, 0, stream>>>(pout, slot0, slot1, out);
}